// Round 1
// baseline (33258.536 us; speedup 1.0000x reference)
//
#include <hip/hip_runtime.h>

// MUCMA sequential scan on a single wave (64 lanes), state entirely in registers.
//
// Lane roles:
//   lanes 0..37  : (t,j) with lane = t*2 + j. Hold w[0][j][t], w[1][j][t] and load u[t][j].
//   lanes 48..53 : g=0 -> r[k=0, l=1, d=lane-48], z[d][1]
//   lanes 56..61 : g=1 -> r[k=1, l=0, d=lane-56], z[d][0]
//   (diagonal r[k,k,*] is never read by the reference - mask kills it - so not tracked)
//
// Cross-lane: DPP adds for reductions (low latency vs ds_swizzle), v_readlane for
// uniform broadcast. Output per step is exactly v(n) (pre-update weights applied to u(n)).

constexpr int   NTAPS  = 19;
constexpr int   FRST   = 38;                  // floats per frame per component (taps*dims)
constexpr float BETA_C = 0.999f;
constexpr float OMB_C  = 0.001f;              // float32(1.0 - 0.999) as the reference computes
constexpr float LR_C   = 0.0001220703125f;    // 2^-13
constexpr float R2_C   = 1.32f;

template <int CTRL>
__device__ __forceinline__ float dpp_mov(float x) {
    return __int_as_float(__builtin_amdgcn_update_dpp(
        0, __float_as_int(x), CTRL, 0xF, 0xF, true));
}

// Wave-wide sum; total lands in lane 63 (classic gfx9 pattern).
__device__ __forceinline__ float wave_sum63(float x) {
    x += dpp_mov<0x111>(x);   // row_shr:1
    x += dpp_mov<0x112>(x);   // row_shr:2
    x += dpp_mov<0x114>(x);   // row_shr:4
    x += dpp_mov<0x118>(x);   // row_shr:8  -> lane15 of each row = row sum
    x += dpp_mov<0x142>(x);   // row_bcast:15
    x += dpp_mov<0x143>(x);   // row_bcast:31 -> lane 63 = wave total
    return x;
}

__device__ __forceinline__ float rdlane(float x, int l) {
    return __int_as_float(__builtin_amdgcn_readlane(__float_as_int(x), l));
}

struct St {
    float w0r, w0i, w1r, w1i;   // w[0][j][t], w[1][j][t] (lanes 0..37)
    float r_re, r_im;           // r[k,1-k,d] (r-lanes)
    float z_re, z_im;           // z[d][1-k]  (r-lanes)
    float bp;                   // beta^(n+1), uniform
};

__device__ __forceinline__ void mucma_step(
    St& s, float u_re, float u_im, int n,
    int lane, int d, bool gq, float qmask,
    float* __restrict__ out)
{
    // ---- v = sum_{j,t} w[i][j][t] * u[t][j] ----
    float p0r = s.w0r * u_re - s.w0i * u_im;
    float p0i = s.w0r * u_im + s.w0i * u_re;
    float p1r = s.w1r * u_re - s.w1i * u_im;
    float p1i = s.w1r * u_im + s.w1i * u_re;
    p0r = wave_sum63(p0r);
    p0i = wave_sum63(p0i);
    p1r = wave_sum63(p1r);
    p1i = wave_sum63(p1i);
    const float v0r = rdlane(p0r, 63);
    const float v0i = rdlane(p0i, 63);
    const float v1r = rdlane(p1r, 63);
    const float v1i = rdlane(p1i, 63);

    // per-lane v[k] / v[l] for the r-lanes (k = gq, l = 1-k)
    const float vkr = gq ? v1r : v0r;
    const float vki = gq ? v1i : v0i;
    const float vlr = gq ? v0r : v1r;
    const float vli = gq ? v0i : v1i;

    // ---- z shift: z_new[0] = v[l], z_new[d] = z_old[d-1] ----
    const float zsr = dpp_mov<0x111>(s.z_re);
    const float zsi = dpp_mov<0x111>(s.z_im);
    s.z_re = (d == 0) ? vlr : zsr;
    s.z_im = (d == 0) ? vli : zsi;

    // ---- r = beta*r + (1-beta) * v[k] * conj(z) ----
    const float ar = OMB_C * vkr, ai = OMB_C * vki;
    s.r_re = BETA_C * s.r_re + (ar * s.z_re + ai * s.z_im);
    s.r_im = BETA_C * s.r_im + (ai * s.z_re - ar * s.z_im);

    // ---- mu partial: q = r * conj(z), masked to the 12 live lanes ----
    float qr = (s.r_re * s.z_re + s.r_im * s.z_im) * qmask;
    float qi = (s.r_im * s.z_re - s.r_re * s.z_im) * qmask;
    // sum the 6 d-terms inside each aligned 8-group (prefix-sum; lanes 55/63 clean)
    qr += dpp_mov<0x111>(qr); qi += dpp_mov<0x111>(qi);
    qr += dpp_mov<0x112>(qr); qi += dpp_mov<0x112>(qi);
    qr += dpp_mov<0x114>(qr); qi += dpp_mov<0x114>(qi);
    // lane 55 holds sum_d r[0,1,d]*conj(z[d][1]) ; lane 63 the k=1 counterpart

    // ---- bias correction ----
    const float inv = __builtin_amdgcn_rcpf(1.0f - s.bp);
    s.bp *= BETA_C;

    // ---- c'[k] = LR * (-2*e_k*v_k + 2*inv*mu_k)  (valid in lanes 55 and 63) ----
    const float ek  = R2_C - (vkr * vkr + vki * vki);
    const float c_r = LR_C * (-2.0f * ek * vkr + 2.0f * inv * qr);
    const float c_i = LR_C * (-2.0f * ek * vki + 2.0f * inv * qi);
    const float c0r = rdlane(c_r, 55), c0i = rdlane(c_i, 55);
    const float c1r = rdlane(c_r, 63), c1i = rdlane(c_i, 63);

    // ---- w -= c' * conj(u)  (u==0 on non-w lanes, so their w stays 0) ----
    s.w0r -= c0r * u_re + c0i * u_im;
    s.w0i -= c0i * u_re - c0r * u_im;
    s.w1r -= c1r * u_re + c1i * u_im;
    s.w1i -= c1i * u_re - c1r * u_im;

    // ---- emit v(n): out[n][i][{re,im}] ----
    if (lane == 0) {
        float4 o;
        o.x = v0r; o.y = v0i; o.z = v1r; o.w = v1i;
        *reinterpret_cast<float4*>(out + 4 * n) = o;
    }
}

__global__ void __launch_bounds__(64, 1)
mucma_scan_kernel(const float* __restrict__ fr_re, const float* __restrict__ fr_im,
                  const float* __restrict__ w0r_in, const float* __restrict__ w0i_in,
                  float* __restrict__ out, int nsym)
{
    const int  lane = threadIdx.x;
    const bool is_w = lane < FRST;
    const int  t = lane >> 1, j = lane & 1;

    St s;
    s.w0r = 0.f; s.w0i = 0.f; s.w1r = 0.f; s.w1i = 0.f;
    if (is_w) {
        s.w0r = w0r_in[j * NTAPS + t];          // w[0][j][t]
        s.w0i = w0i_in[j * NTAPS + t];
        s.w1r = w0r_in[FRST + j * NTAPS + t];   // w[1][j][t]
        s.w1i = w0i_in[FRST + j * NTAPS + t];
    }
    s.r_re = 0.f; s.r_im = 0.f; s.z_re = 0.f; s.z_im = 0.f;
    s.bp = BETA_C;

    const int   d     = lane & 7;
    const bool  gq    = lane >= 56;
    const float qmask = (lane >= 48 && d < 6) ? 1.0f : 0.0f;
    const int   uoff  = is_w ? lane : 0;

    // 8-deep register ring prefetch of u frames
    float ure[8], uim[8];
#pragma unroll
    for (int p = 0; p < 8; ++p) {
        const float lr = fr_re[p * FRST + uoff];
        const float li = fr_im[p * FRST + uoff];
        ure[p] = is_w ? lr : 0.f;
        uim[p] = is_w ? li : 0.f;
    }

    const int nmain = nsym & ~7;
    for (int nb = 0; nb < nmain; nb += 8) {
#pragma unroll
        for (int p = 0; p < 8; ++p) {
            const int n = nb + p;
            const float u_re = ure[p], u_im = uim[p];
            // prefetch u(n+8)
            {
                int np = n + 8;
                if (np > nsym - 1) np = nsym - 1;
                const float lr = fr_re[np * FRST + uoff];
                const float li = fr_im[np * FRST + uoff];
                ure[p] = is_w ? lr : 0.f;
                uim[p] = is_w ? li : 0.f;
            }
            mucma_step(s, u_re, u_im, n, lane, d, gq, qmask, out);
        }
    }
    // tail (not taken for nsym = 131072)
    for (int n = nmain; n < nsym; ++n) {
        const float lr = fr_re[n * FRST + uoff];
        const float li = fr_im[n * FRST + uoff];
        const float u_re = is_w ? lr : 0.f;
        const float u_im = is_w ? li : 0.f;
        mucma_step(s, u_re, u_im, n, lane, d, gq, qmask, out);
    }
}

extern "C" void kernel_launch(void* const* d_in, const int* in_sizes, int n_in,
                              void* d_out, int out_size, void* d_ws, size_t ws_size,
                              hipStream_t stream)
{
    const float* fr_re = (const float*)d_in[0];
    const float* fr_im = (const float*)d_in[1];
    const float* w0r   = (const float*)d_in[2];
    const float* w0i   = (const float*)d_in[3];
    float* out = (float*)d_out;
    const int nsym = in_sizes[0] / FRST;
    hipLaunchKernelGGL(mucma_scan_kernel, dim3(1), dim3(64), 0, stream,
                       fr_re, fr_im, w0r, w0i, out, nsym);
}